// Round 5
// baseline (357.633 us; speedup 1.0000x reference)
//
#include <hip/hip_runtime.h>

typedef int intx4 __attribute__((ext_vector_type(4)));
typedef int intx8 __attribute__((ext_vector_type(8)));
typedef float floatx4 __attribute__((ext_vector_type(4)));

#define M_DIM 8192
#define N_DIM 4096
#define K_DIM 4096
#define KB2 (K_DIM / 2)   // bytes per packed fp4 row

#define PACK_BLOCKS 2048
#define NF4_X ((size_t)M_DIM * K_DIM / 4)              // float4 count of x
#define NF4_TOT (NF4_X + (size_t)N_DIM * K_DIM / 4)    // + float4 count of W

// async global->LDS, 16B per lane. LDS dest is wave-uniform base + lane*16.
__device__ __forceinline__ void gld_lds16(const char* g, char* l) {
  __builtin_amdgcn_global_load_lds(
      (const __attribute__((address_space(1))) unsigned int*)g,
      (__attribute__((address_space(3))) unsigned int*)l,
      16, 0, 0);
}

// fp4 e2m1 sign nibble: +1 -> 0x2, -1 -> 0xA, 0 -> 0x0
__device__ __forceinline__ unsigned nib(float v) {
  return v > 0.0f ? 0x2u : (v < 0.0f ? 0xAu : 0x0u);
}

// Fully-coalesced pack: one float4 read / one ushort write per lane-iteration.
__global__ __launch_bounds__(256) void pack_kernel(const float* __restrict__ x,
                                                   const float* __restrict__ Wm,
                                                   unsigned short* __restrict__ pk,
                                                   double* __restrict__ accd) {
  const int t = threadIdx.x;
  const size_t stride = (size_t)PACK_BLOCKS * 256;
  const float4* __restrict__ X4 = (const float4*)x;
  const float4* __restrict__ W4 = (const float4*)Wm;
  float s = 0.0f;
  for (size_t i = (size_t)blockIdx.x * 256 + t; i < NF4_TOT; i += stride) {
    float4 v;
    if (i < NF4_X) {
      v = X4[i];
      s += fabsf(v.x) + fabsf(v.y) + fabsf(v.z) + fabsf(v.w);
    } else {
      v = W4[i - NF4_X];
    }
    pk[i] = (unsigned short)(nib(v.x) | (nib(v.y) << 4) | (nib(v.z) << 8) |
                             (nib(v.w) << 12));
  }
  #pragma unroll
  for (int off = 32; off > 0; off >>= 1) s += __shfl_down(s, off);
  __shared__ float sp[4];
  if ((t & 63) == 0) sp[t >> 6] = s;
  __syncthreads();
  if (t == 0) atomicAdd(accd, (double)(sp[0] + sp[1] + sp[2] + sp[3]));
}

// C = Xb (M x K, fp4) * Wb^T (N x K, fp4); out[m][n] = (dot + bias[n]) * scale
//
// 256x256 tile / 512 threads (8 waves, 2M x 4N) / per-wave 8x4 frags of
// 16x16x128 fp4 (unit scales).
//
// 4-phase fine interleave (m201 8-phase template port): each K-tile (BK=128)
// is 4 barrier-delimited phases:
//   { ds_read 2 A-frags (+4 B-frags in ph0) | issue 1 staging gld_lds |
//     barrier | setprio(1) 8 MFMA setprio(0) | barrier }
// Coarse {stage->wait->bar->compute->bar} (rounds 0-3) left MFMA and LDS
// pipes <40% busy each: with 2 waves/SIMD in lockstep, reads and MFMAs never
// overlap across waves. Phase barriers stagger them (m233/m196 mechanism).
//
// Staging: 2-tile lead, 3 LDS tile-buffers (96 KB — free, registers cap us
// at 1 block/CU regardless), 4 gld_lds spread 1/phase, s_waitcnt vmcnt(4)
// once per tile (next tile's 4 loads stay in flight; never 0 until the tail).
// Buffer indices all compile-time via 3x unrolled rotation (round-1 lesson).
//
// LDS layout per buffer (16 KB per matrix): row pairs interleaved into 128-B
// lines: addr(r, c) = (r>>1)*128 + c*32 + (r&1)*16, slot c of row r holds
// global 16B k-chunk g = (c + (r>>1)) & 3 (swizzle on the global source since
// global_load_lds dests are lane-linear). Measured 0 bank conflicts.
__global__ __launch_bounds__(512, 2) void gemm_kernel(const char* __restrict__ Xb,
                                                      const char* __restrict__ Wb,
                                                      const float* __restrict__ bias,
                                                      const double* __restrict__ accd,
                                                      float* __restrict__ out) {
  __shared__ __align__(16) char lA[3][16384];
  __shared__ __align__(16) char lB[3][16384];
  const int t = threadIdx.x;
  const int lane = t & 63;
  const int w = t >> 6;            // wave 0..7
  const int m16 = lane & 15;
  const int quad = lane >> 4;      // 0..3 -> k-chunk of 32 fp4 (16 B)
  const int bM = blockIdx.y * 256;
  const int bN = blockIdx.x * 256;
  const int waveM = (w >> 2) * 128;    // 0 or 128
  const int waveN = (w & 3) * 64;      // 0,64,128,192

  // staging: thread t covers local row srl in [0,128), slot ssc; LDS
  // addr(srl,ssc) == t*16 (lane-linear). Swizzle chunk g identical for
  // srl and srl+128, so it folds into the global base pointers.
  const int srl = 2 * (t >> 3) + (t & 1);
  const int ssc = (t >> 1) & 3;
  const int g0 = (ssc + (srl >> 1)) & 3;
  const char* gA = Xb + (size_t)(bM + srl) * KB2 + g0 * 16;
  const char* gB = Wb + (size_t)(bN + srl) * KB2 + g0 * 16;
  const int ldst = w * 1024;       // wave-uniform LDS dest offset

  // per-wave ds_read byte offsets — loop-invariant
  int offA[8], offB[4];
  #pragma unroll
  for (int i = 0; i < 8; ++i) {
    const int m = waveM + i * 16 + m16;
    offA[i] = (m >> 1) * 128 + (((quad - (m >> 1)) & 3)) * 32 + (m & 1) * 16;
  }
  #pragma unroll
  for (int j = 0; j < 4; ++j) {
    const int n = waveN + j * 16 + m16;
    offB[j] = (n >> 1) * 128 + (((quad - (n >> 1)) & 3)) * 32 + (n & 1) * 16;
  }

  floatx4 acc[8][4];
  #pragma unroll
  for (int i = 0; i < 8; ++i)
    #pragma unroll
    for (int j = 0; j < 4; ++j)
      acc[i][j] = (floatx4){0.0f, 0.0f, 0.0f, 0.0f};

#define WAITV4() asm volatile("s_waitcnt vmcnt(4)" ::: "memory")
#define WAITV0() asm volatile("s_waitcnt vmcnt(0)" ::: "memory")
#define BARF()                                  \
  do {                                          \
    __builtin_amdgcn_s_barrier();               \
    asm volatile("" ::: "memory");              \
  } while (0)

#define MM2(I0, L0, L1)                                                      \
  do {                                                                       \
    intx8 a0_ = (intx8){(L0)[0], (L0)[1], (L0)[2], (L0)[3], 0, 0, 0, 0};     \
    intx8 a1_ = (intx8){(L1)[0], (L1)[1], (L1)[2], (L1)[3], 0, 0, 0, 0};     \
    __builtin_amdgcn_s_setprio(1);                                           \
    _Pragma("unroll")                                                        \
    for (int j = 0; j < 4; ++j) {                                            \
      acc[I0][j] = __builtin_amdgcn_mfma_scale_f32_16x16x128_f8f6f4(         \
          a0_, b8[j], acc[I0][j], 4, 4, 0, 0x7F7F7F7F, 0, 0x7F7F7F7F);       \
      acc[(I0) + 1][j] = __builtin_amdgcn_mfma_scale_f32_16x16x128_f8f6f4(   \
          a1_, b8[j], acc[(I0) + 1][j], 4, 4, 0, 0x7F7F7F7F, 0, 0x7F7F7F7F); \
    }                                                                        \
    __builtin_amdgcn_s_setprio(0);                                           \
  } while (0)

// One K-tile: 4 phases. BUF/NXT are literals; TILE may be a runtime value.
// WMODE: 0 = vmcnt(4) in ph3 (steady), 1 = vmcnt(0) (tail drain), 2 = none.
#define ITER(BUF, NXT, TILE, DOSTG, WMODE)                                   \
  do {                                                                       \
    intx8 b8[4];                                                             \
    { /* phase 0: B0..3 + A0,A1 */                                           \
      _Pragma("unroll")                                                      \
      for (int j = 0; j < 4; ++j) {                                          \
        intx4 lo = *(const intx4*)&lB[BUF][offB[j]];                         \
        b8[j] = (intx8){lo[0], lo[1], lo[2], lo[3], 0, 0, 0, 0};             \
      }                                                                      \
      intx4 l0 = *(const intx4*)&lA[BUF][offA[0]];                           \
      intx4 l1 = *(const intx4*)&lA[BUF][offA[1]];                           \
      if (DOSTG) gld_lds16(gA + (size_t)(TILE) * 64, &lA[NXT][ldst]);        \
      BARF(); MM2(0, l0, l1); BARF();                                        \
    }                                                                        \
    { /* phase 1: A2,A3 */                                                   \
      intx4 l0 = *(const intx4*)&lA[BUF][offA[2]];                           \
      intx4 l1 = *(const intx4*)&lA[BUF][offA[3]];                           \
      if (DOSTG)                                                             \
        gld_lds16(gA + (size_t)(TILE) * 64 + (size_t)128 * KB2,              \
                  &lA[NXT][8192 + ldst]);                                    \
      BARF(); MM2(2, l0, l1); BARF();                                        \
    }                                                                        \
    { /* phase 2: A4,A5 */                                                   \
      intx4 l0 = *(const intx4*)&lA[BUF][offA[4]];                           \
      intx4 l1 = *(const intx4*)&lA[BUF][offA[5]];                           \
      if (DOSTG) gld_lds16(gB + (size_t)(TILE) * 64, &lB[NXT][ldst]);        \
      BARF(); MM2(4, l0, l1); BARF();                                        \
    }                                                                        \
    { /* phase 3: A6,A7 + next-buffer-ready wait */                          \
      intx4 l0 = *(const intx4*)&lA[BUF][offA[6]];                           \
      intx4 l1 = *(const intx4*)&lA[BUF][offA[7]];                           \
      if (DOSTG)                                                             \
        gld_lds16(gB + (size_t)(TILE) * 64 + (size_t)128 * KB2,              \
                  &lB[NXT][8192 + ldst]);                                    \
      if ((WMODE) == 0) WAITV4();                                            \
      else if ((WMODE) == 1) WAITV0();                                       \
      BARF(); MM2(6, l0, l1); BARF();                                        \
    }                                                                        \
  } while (0)

  // prologue: stage tiles 0 -> buf0 and 1 -> buf1 (8 loads); wait for tile 0
  // (vmcnt(4): tile 1's four stay in flight), barrier.
  gld_lds16(gA + (size_t)0 * 64, &lA[0][ldst]);
  gld_lds16(gA + (size_t)0 * 64 + (size_t)128 * KB2, &lA[0][8192 + ldst]);
  gld_lds16(gB + (size_t)0 * 64, &lB[0][ldst]);
  gld_lds16(gB + (size_t)0 * 64 + (size_t)128 * KB2, &lB[0][8192 + ldst]);
  gld_lds16(gA + (size_t)1 * 64, &lA[1][ldst]);
  gld_lds16(gA + (size_t)1 * 64 + (size_t)128 * KB2, &lA[1][8192 + ldst]);
  gld_lds16(gB + (size_t)1 * 64, &lB[1][ldst]);
  gld_lds16(gB + (size_t)1 * 64 + (size_t)128 * KB2, &lB[1][8192 + ldst]);
  WAITV4();
  BARF();

  // steady state: tiles 0..29 in groups of 3 (buffer rotation 0,1,2),
  // iter j computes tile j from buf j%3 and stages tile j+2 into (j+2)%3.
  for (int g = 0; g < 10; ++g) {
    const int t3 = g * 3;
    ITER(0, 2, t3 + 2, 1, 0);
    ITER(1, 0, t3 + 3, 1, 0);
    ITER(2, 1, t3 + 4, 1, 0);
  }
  // tail: tile 30 (drain tile 31's loads), tile 31 (nothing outstanding)
  ITER(0, 2, 0, 0, 1);
  ITER(1, 0, 0, 0, 2);
#undef ITER
#undef MM2
#undef WAITV4
#undef WAITV0
#undef BARF

  const float scale = (float)(*accd * (1.0 / (double)((size_t)M_DIM * K_DIM)));

  // C/D layout (shape-determined): col = lane&15, row = quad*4 + reg
  #pragma unroll
  for (int j = 0; j < 4; ++j) {
    const int col = bN + waveN + j * 16 + m16;
    const float bj = bias[col];
    #pragma unroll
    for (int i = 0; i < 8; ++i) {
      const size_t row0 = (size_t)(bM + waveM + i * 16 + quad * 4);
      float* po = out + row0 * N_DIM + col;
      #pragma unroll
      for (int r = 0; r < 4; ++r)
        po[(size_t)r * N_DIM] = (acc[i][j][r] + bj) * scale;
    }
  }
}

extern "C" void kernel_launch(void* const* d_in, const int* in_sizes, int n_in,
                              void* d_out, int out_size, void* d_ws, size_t ws_size,
                              hipStream_t stream) {
  const float* x = (const float*)d_in[0];   // [8192, 4096]
  const float* W = (const float*)d_in[1];   // [4096, 4096]
  const float* b = (const float*)d_in[2];   // [4096]
  float* out = (float*)d_out;               // [8192, 4096]

  double* accd = (double*)d_ws;                                   // 8B |x| sum
  char* Xb = (char*)d_ws + 256;                                   // 16 MiB sign(x) fp4
  char* Wb = (char*)d_ws + 256 + (size_t)M_DIM * K_DIM / 2;       // 8 MiB sign(W) fp4

  hipMemsetAsync(d_ws, 0, 8, stream);   // zero the reduction accumulator (ws is poisoned)
  pack_kernel<<<PACK_BLOCKS, 256, 0, stream>>>(x, W, (unsigned short*)Xb, accd);
  gemm_kernel<<<dim3(N_DIM / 256, M_DIM / 256), 512, 0, stream>>>(Xb, Wb, b, accd, out);
}